// Round 11
// baseline (12499.673 us; speedup 1.0000x reference)
//
#include <hip/hip_runtime.h>
#include <hip/hip_bf16.h>
#include <stdint.h>

typedef __bf16 bf16_t;
typedef __bf16 bf16x8 __attribute__((ext_vector_type(8)));
typedef float f32x4 __attribute__((ext_vector_type(4)));

#define AS1(p) ((const __attribute__((address_space(1))) void*)(uintptr_t)(p))
#define AS3(p) ((__attribute__((address_space(3))) void*)(uintptr_t)(p))

__device__ __forceinline__ void gload16(const bf16_t* g, bf16_t* l) {
  __builtin_amdgcn_global_load_lds(AS1(g), AS3(l), 16, 0, 0);
}

#define SB()      __builtin_amdgcn_sched_barrier(0);
#define VMCNT(n)  asm volatile("s_waitcnt vmcnt(" #n ")" ::: "memory");
#define LGKM(n)   asm volatile("s_waitcnt lgkmcnt(" #n ")" ::: "memory");

// ===== 256x256 GEMM core (B^T form), BK=32 half-windows, 64KB LDS, 2 blocks/CU =====
// C[m][n] = sum_k A[m][k]*B[n][k]. 512 threads = 8 waves (2M x 4N), per-wave 128x64.
// K in 32-wide halves; LDS = 2 slots x 32KB (A 16K | B 16K) = 64 KiB -> with VGPR<=128
// (launch_bounds 512,4) TWO blocks co-reside per CU (16 waves). m114 mechanism: the
// other block's MFMAs cover this block's vmcnt/barrier stalls - the TLP that all
// 1-block schedule variants (R3-R10, 37-47% MfmaUtil) lacked.
// Half layout [256 rows][32 k] bf16, XOR swizzle byte^=((byte>>7)&7)<<4 (write: linear
// LDS dest + pre-swizzled global source; read: same XOR) -> 0 bank conflicts (proven).
// Window w (slot s=w&1): vmcnt(0); BAR; SB; 12 ds_reads(s); stage half w+1 -> s^1
// (4 gloads); 32 MFMA (setprio); lgkm0.
// Races: RAW - each wave drains its OWN loads (vmcnt0) before the shared barrier, so
// all waves' stages have landed before any wave reads. WAR - stage(w+1) targets the
// slot read in window w-1; those reads were lgkm0-drained before each wave reached
// BAR(w), and the stage is issued after BAR(w). vmcnt(0) is count-independent ->
// immune to spills / compiler-inserted VMEM (no counted-ledger fragility).
__device__ __forceinline__ void gemm256(const bf16_t* __restrict__ A, int lda,
                                        const bf16_t* __restrict__ B, int ldb,
                                        int nt, f32x4 acc[8][4], bf16_t* lds) {
  const int t = (int)threadIdx.x;
  const int lane = t & 63, wv = t >> 6;
  const int wr = wv >> 2, wc = wv & 3;
  const int fr = lane & 15, fq = lane >> 4;
  char* ldsb = (char*)lds;

  // staging: thread t writes LDS bytes [t*16,+16) of each 8KB line (linear);
  // global source pre-swizzled so the swizzled read sees the right data
  const int s0 = (t * 16) ^ (((t >> 3) & 7) << 4);
  const int r0 = s0 >> 6, q0 = (s0 >> 4) & 3;
  const bf16_t* gA0 = A + (size_t)r0 * lda + q0 * 8;
  const bf16_t* gA1 = gA0 + (size_t)128 * lda;
  const bf16_t* gB0 = B + (size_t)r0 * ldb + q0 * 8;
  const bf16_t* gB1 = gB0 + (size_t)128 * ldb;

  // frag read bases (bytes within a 32KB slot), same XOR (bits[9:7]=fr>>1)
  const int swz = (fr * 64 + fq * 16) ^ (((fr >> 1) & 7) << 4);
  const int abase = wr * 8192 + swz;          // A region [0,16K): +qm*4096 +i*1024
  const int bbase = 16384 + wc * 4096 + swz;  // B region [16K,32K): +n*1024

  bf16x8 bb[4], aa0[4], aa1[4];

#define STAGE(sl, kof) { \
    bf16_t* _d = lds + (sl) * 16384; \
    gload16(gA0 + (kof), _d + t * 8); \
    gload16(gA1 + (kof), _d + 4096 + t * 8); \
    gload16(gB0 + (kof), _d + 8192 + t * 8); \
    gload16(gB1 + (kof), _d + 12288 + t * 8); }
#define READS(sl) { \
    const char* _s = ldsb + (sl) * 32768; \
    _Pragma("unroll") for (int n = 0; n < 4; ++n) bb[n] = *(const bf16x8*)(_s + bbase + n * 1024); \
    _Pragma("unroll") for (int i = 0; i < 4; ++i) aa0[i] = *(const bf16x8*)(_s + abase + i * 1024); \
    _Pragma("unroll") for (int i = 0; i < 4; ++i) aa1[i] = *(const bf16x8*)(_s + abase + 4096 + i * 1024); }
#define MFMA16(dst, qm) { \
    _Pragma("unroll") for (int i = 0; i < 4; ++i) \
      _Pragma("unroll") for (int n = 0; n < 4; ++n) \
        acc[(qm) * 4 + i][n] = __builtin_amdgcn_mfma_f32_16x16x32_bf16(dst[i], bb[n], acc[(qm) * 4 + i][n], 0, 0, 0); }

  const int H = nt * 2;  // number of 32-wide k-halves
  STAGE(0, 0)            // prologue: half 0 -> slot 0
  int kof = 32;
  for (int ww = 0; ww < H - 1; ++ww, kof += 32) {
    const int sl = ww & 1;
    VMCNT(0) __builtin_amdgcn_s_barrier(); SB()
    READS(sl)
    STAGE(sl ^ 1, kof)   // half ww+1 -> other slot (WAR-safe: post-BAR(ww))
    __builtin_amdgcn_s_setprio(1);
    MFMA16(aa0, 0)
    MFMA16(aa1, 1)
    __builtin_amdgcn_s_setprio(0);
    LGKM(0)              // reads of slot sl drained before next window's BAR
  }
  {  // tail half: reads only
    VMCNT(0) __builtin_amdgcn_s_barrier(); SB()
    READS((H - 1) & 1)
    __builtin_amdgcn_s_setprio(1);
    MFMA16(aa0, 0)
    MFMA16(aa1, 1)
    __builtin_amdgcn_s_setprio(0);
  }
#undef STAGE
#undef READS
#undef MFMA16
}

#define EPI_VARS \
  const int t = (int)threadIdx.x; \
  const int lane = t & 63, w = t >> 6; \
  const int wr = w >> 2, wc = w & 3; \
  const int fr = lane & 15, fq = lane >> 4;

#define ZERO8x4(acc) \
  _Pragma("unroll") for (int _i = 0; _i < 8; ++_i) \
  _Pragma("unroll") for (int _j = 0; _j < 4; ++_j) { f32x4 _z = {0.f,0.f,0.f,0.f}; acc[_i][_j] = _z; }

// ---------------- conversions ----------------
__global__ void k_cvt(const float* __restrict__ s, bf16_t* __restrict__ d, long n8) {
  long i = (long)blockIdx.x * blockDim.x + threadIdx.x;
  long st = (long)gridDim.x * blockDim.x;
  for (; i < n8; i += st) {
    const float4* sp = (const float4*)(s + i * 8);
    float4 a = sp[0], b = sp[1];
    bf16x8 v;
    v[0] = (__bf16)a.x; v[1] = (__bf16)a.y; v[2] = (__bf16)a.z; v[3] = (__bf16)a.w;
    v[4] = (__bf16)b.x; v[5] = (__bf16)b.y; v[6] = (__bf16)b.z; v[7] = (__bf16)b.w;
    *(bf16x8*)(d + i * 8) = v;
  }
}

__global__ void k_fill(float* o, float v, long n) {
  long i = (long)blockIdx.x * blockDim.x + threadIdx.x;
  long st = (long)gridDim.x * blockDim.x;
  for (; i < n; i += st) o[i] = v;
}

// ---------------- GEMM 1: QKV projection (256-tile) ----------------
__global__ __launch_bounds__(512, 4) void k_qkv256(
    const bf16_t* __restrict__ xb, const bf16_t* __restrict__ Wb,
    const float* __restrict__ bq, const float* __restrict__ bk, const float* __restrict__ bv,
    bf16_t* __restrict__ Q, bf16_t* __restrict__ K, bf16_t* __restrict__ Vt) {
  __shared__ __align__(16) bf16_t lds[32768];
  int bid = (int)blockIdx.x;
  int id = (bid & 7) * 384 + (bid >> 3);  // XCD-bijective swizzle (3072 = 8*384)
  EPI_VARS
  f32x4 acc[8][4];
  ZERO8x4(acc)

  bool vmode = id >= 2048;
  int mt = 0, ntile = 0, tok = 0, wm = 0;
  const bf16_t *Ap, *Bp;
  if (!vmode) {
    mt = id & 127; ntile = id >> 7;  // B-panel-major: resident blocks share W panel
    Ap = xb + (size_t)mt * 256 * 2048;
    Bp = Wb + (size_t)ntile * 256 * 2048;
  } else {
    int vb = id - 2048;
    tok = vb & 127; wm = vb >> 7;
    Ap = Wb + (size_t)(16 + wm) * 256 * 2048;
    Bp = xb + (size_t)tok * 256 * 2048;
  }
  gemm256(Ap, 2048, Bp, 2048, 32, acc, lds);

  if (!vmode) {
    int sel = ntile >> 3;  // 0 -> Q, 1 -> K
    const float* bias = sel ? bk : bq;
    bf16_t* dst = sel ? K : Q;
    int cbase = (ntile & 7) * 256 + wc * 64;
#pragma unroll
    for (int ni = 0; ni < 4; ++ni) {
      int c2 = cbase + ni * 16 + fr;  // [0,2048)
      int h = c2 >> 10, d = c2 & 1023;
      float bb = bias[c2];
#pragma unroll
      for (int mi = 0; mi < 8; ++mi) {
        f32x4 a = acc[mi][ni];
#pragma unroll
        for (int r = 0; r < 4; ++r) {
          int m = mt * 256 + wr * 128 + mi * 16 + fq * 4 + r;
          int b = m >> 10, tk = m & 1023;
          dst[(((size_t)(b * 2 + h) << 10) + tk) * 1024 + d] = (bf16_t)(a[r] + bb);
        }
      }
    }
  } else {
#pragma unroll
    for (int mi = 0; mi < 8; ++mi) {
#pragma unroll
      for (int r = 0; r < 4; ++r) {
        int gd = wm * 256 + wr * 128 + mi * 16 + fq * 4 + r;  // [0,2048)
        int h = gd >> 10, dd = gd & 1023;
        float bb = bv[gd];
#pragma unroll
        for (int ni = 0; ni < 4; ++ni) {
          int m = tok * 256 + wc * 64 + ni * 16 + fr;
          int b = m >> 10, tk = m & 1023;
          Vt[(((size_t)(b * 2 + h) << 10) + dd) * 1024 + tk] = (bf16_t)(acc[mi][ni][r] + bb);
        }
      }
    }
  }
}

// ---------------- GEMM 2: S = Q K^T * scale (lower-tri 256-tiles, bf16 out) --------
__global__ __launch_bounds__(512, 4) void k_s256(const bf16_t* __restrict__ Q,
                                                 const bf16_t* __restrict__ K,
                                                 bf16_t* __restrict__ S, int pbase) {
  __shared__ __align__(16) bf16_t lds[32768];
  int id = (int)blockIdx.x;
  int pc = id / 10, rem = id % 10;
  int ti = 0;
  while (rem > ti) { rem -= ti + 1; ++ti; }
  int tj = rem;
  size_t p = (size_t)(pbase + pc);
  EPI_VARS
  f32x4 acc[8][4];
  ZERO8x4(acc)
  gemm256(Q + (p << 20) + (size_t)ti * 256 * 1024, 1024,
          K + (p << 20) + (size_t)tj * 256 * 1024, 1024, 16, acc, lds);
  bf16_t* Sp = S + ((size_t)pc << 20);
  const float scale = 0.022097086912079608f;  // 1/sqrt(2048)
#pragma unroll
  for (int mi = 0; mi < 8; ++mi)
#pragma unroll
    for (int ni = 0; ni < 4; ++ni) {
      int col = tj * 256 + wc * 64 + ni * 16 + fr;
      f32x4 a = acc[mi][ni];
#pragma unroll
      for (int r = 0; r < 4; ++r) {
        int row = ti * 256 + wr * 128 + mi * 16 + fq * 4 + r;
        Sp[((size_t)row << 10) + col] = (bf16_t)(a[r] * scale);
      }
    }
}

// ------- softmax: one ROW per wave (4 rows/block), vectorized bf16x8, causal -------
__global__ __launch_bounds__(256) void k_softmax(const bf16_t* __restrict__ S,
                                                 bf16_t* __restrict__ P) {
  int gw = (int)blockIdx.x * 4 + ((int)threadIdx.x >> 6);
  int pc = gw >> 10, row = gw & 1023;
  int lane = (int)threadIdx.x & 63;
  const bf16_t* s = S + ((size_t)pc << 20) + ((size_t)row << 10);
  bf16_t* p = P + ((size_t)pc << 20) + ((size_t)row << 10);
  int cend = ((row >> 8) + 1) << 8;  // 256-aligned (PV K-tile width)
  bf16x8 v0 = *(const bf16x8*)(s + lane * 8);
  bf16x8 v1 = *(const bf16x8*)(s + 512 + lane * 8);
  float x[16];
  float mx = -1e30f;
#pragma unroll
  for (int j = 0; j < 8; ++j) {
    int c0 = lane * 8 + j, c1 = 512 + lane * 8 + j;
    x[j]     = (c0 <= row) ? (float)v0[j] : -1e30f;
    x[8 + j] = (c1 <= row) ? (float)v1[j] : -1e30f;
    mx = fmaxf(mx, fmaxf(x[j], x[8 + j]));
  }
  for (int o = 32; o > 0; o >>= 1) mx = fmaxf(mx, __shfl_xor(mx, o));
  float sum = 0.f;
#pragma unroll
  for (int j = 0; j < 16; ++j) {
    x[j] = (x[j] > -1e29f) ? __expf(x[j] - mx) : 0.f;
    sum += x[j];
  }
  for (int o = 32; o > 0; o >>= 1) sum += __shfl_xor(sum, o);
  float inv = 1.f / sum;
  bf16x8 o0, o1;
#pragma unroll
  for (int j = 0; j < 8; ++j) {
    o0[j] = (bf16_t)(x[j] * inv);
    o1[j] = (bf16_t)(x[8 + j] * inv);
  }
  if (lane * 8 < cend)       *(bf16x8*)(p + lane * 8) = o0;
  if (512 + lane * 8 < cend) *(bf16x8*)(p + 512 + lane * 8) = o1;
}

// ---------------- GEMM 3: O = P * V (V pre-transposed; causal-shortened K) ---------
__global__ __launch_bounds__(512, 4) void k_pv256(const bf16_t* __restrict__ P,
                                                  const bf16_t* __restrict__ Vt,
                                                  bf16_t* __restrict__ O, int pbase) {
  __shared__ __align__(16) bf16_t lds[32768];
  int id = (int)blockIdx.x;
  int pc = id >> 4, rem = id & 15;
  int ti = rem >> 2, dj = rem & 3;
  size_t p = (size_t)(pbase + pc);
  EPI_VARS
  f32x4 acc[8][4];
  ZERO8x4(acc)
  gemm256(P + ((size_t)pc << 20) + (size_t)ti * 256 * 1024, 1024,
          Vt + (p << 20) + (size_t)dj * 256 * 1024, 1024, (ti + 1) * 4, acc, lds);
  int b = (int)(p >> 1), h = (int)(p & 1);
#pragma unroll
  for (int mi = 0; mi < 8; ++mi)
#pragma unroll
    for (int ni = 0; ni < 4; ++ni) {
      int dcol = dj * 256 + wc * 64 + ni * 16 + fr;
      f32x4 a = acc[mi][ni];
#pragma unroll
      for (int r = 0; r < 4; ++r) {
        int tk = ti * 256 + wr * 128 + mi * 16 + fq * 4 + r;
        O[(((size_t)b << 10) + tk) * 2048 + (h << 10) + dcol] = (bf16_t)a[r];
      }
    }
}

// ---------------- GEMM 4: out = O * Wo^T (fp32 out) ----------------
__global__ __launch_bounds__(512, 4) void k_out256(const bf16_t* __restrict__ O,
                                                   const bf16_t* __restrict__ W,
                                                   float* __restrict__ out) {
  __shared__ __align__(16) bf16_t lds[32768];
  int bid = (int)blockIdx.x;
  int id = (bid & 7) * 128 + (bid >> 3);  // XCD swizzle (1024 = 8*128)
  int mt = id & 127, ntile = id >> 7;     // B-panel-major
  EPI_VARS
  f32x4 acc[8][4];
  ZERO8x4(acc)
  gemm256(O + (size_t)mt * 256 * 2048, 2048, W + (size_t)ntile * 256 * 2048, 2048, 32, acc, lds);
#pragma unroll
  for (int mi = 0; mi < 8; ++mi)
#pragma unroll
    for (int ni = 0; ni < 4; ++ni) {
      int col = ntile * 256 + wc * 64 + ni * 16 + fr;
      f32x4 a = acc[mi][ni];
#pragma unroll
      for (int r = 0; r < 4; ++r) {
        int row = mt * 256 + wr * 128 + mi * 16 + fq * 4 + r;
        out[(size_t)row * 2048 + col] = a[r];
      }
    }
}

// ---------------- launch ----------------
extern "C" void kernel_launch(void* const* d_in, const int* in_sizes, int n_in,
                              void* d_out, int out_size, void* d_ws, size_t ws_size,
                              hipStream_t stream) {
  const float* x  = (const float*)d_in[0];
  const float* Wq = (const float*)d_in[1];
  const float* bq = (const float*)d_in[2];
  const float* Wk = (const float*)d_in[3];
  const float* bk = (const float*)d_in[4];
  const float* Wv = (const float*)d_in[5];
  const float* bv = (const float*)d_in[6];
  const float* Wo = (const float*)d_in[7];
  float* out = (float*)d_out;

  const size_t MiB = 1ull << 20;
  char* w = (char*)d_ws;
  bf16_t* xb    = (bf16_t*)w;               // 128 MiB, reused as O after QKV
  bf16_t* Ob    = xb;
  bf16_t* Qb    = (bf16_t*)(w + 128 * MiB); // 128 MiB
  bf16_t* Kb    = (bf16_t*)(w + 256 * MiB); // 128 MiB
  bf16_t* Vt    = (bf16_t*)(w + 384 * MiB); // 128 MiB (transposed V)
  bf16_t* Wqkvb = (bf16_t*)(w + 512 * MiB); // 24 MiB  [Wq;Wk;Wv]
  bf16_t* Wob   = (bf16_t*)(w + 536 * MiB); // 8 MiB
  bf16_t* Sc    = (bf16_t*)(w + 544 * MiB); // NP * 2 MiB (bf16)

  size_t rem = ws_size > 544 * MiB ? ws_size - 544 * MiB : 0;
  int NP = (int)(rem / (4 * MiB));
  if (NP > 64) NP = 64;
  if (NP < 1) {
    k_fill<<<2048, 256, 0, stream>>>(out, (float)(ws_size >> 20), (long)out_size);
    return;
  }
  bf16_t* Pc = (bf16_t*)(w + 544 * MiB + (size_t)NP * 2 * MiB); // NP * 2 MiB

  // conversions to bf16
  k_cvt<<<2048, 256, 0, stream>>>(x, xb, 8388608L);
  k_cvt<<<1024, 256, 0, stream>>>(Wq, Wqkvb, 524288L);
  k_cvt<<<1024, 256, 0, stream>>>(Wk, Wqkvb + 4194304, 524288L);
  k_cvt<<<1024, 256, 0, stream>>>(Wv, Wqkvb + 8388608, 524288L);
  k_cvt<<<1024, 256, 0, stream>>>(Wo, Wob, 524288L);

  // QKV projection (Q,K normal layout; V transposed)
  k_qkv256<<<3072, 512, 0, stream>>>(xb, Wqkvb, bq, bk, bv, Qb, Kb, Vt);

  // attention, chunked over (b,h) pairs to bound scratch
  for (int base = 0; base < 64; base += NP) {
    int np = (64 - base) < NP ? (64 - base) : NP;
    k_s256<<<np * 10, 512, 0, stream>>>(Qb, Kb, Sc, base);
    k_softmax<<<np * 256, 256, 0, stream>>>(Sc, Pc);
    k_pv256<<<np * 16, 512, 0, stream>>>(Pc, Vt, Ob, base);
  }

  // output projection
  k_out256<<<1024, 512, 0, stream>>>(Ob, Wob, out);
}

// Round 12
// 1722.542 us; speedup vs baseline: 7.2565x; 7.2565x over previous
//
#include <hip/hip_runtime.h>
#include <hip/hip_bf16.h>
#include <stdint.h>

typedef __bf16 bf16_t;
typedef __bf16 bf16x8 __attribute__((ext_vector_type(8)));
typedef float f32x4 __attribute__((ext_vector_type(4)));

#define AS1(p) ((const __attribute__((address_space(1))) void*)(uintptr_t)(p))
#define AS3(p) ((__attribute__((address_space(3))) void*)(uintptr_t)(p))

__device__ __forceinline__ void gload16(const bf16_t* g, bf16_t* l) {
  __builtin_amdgcn_global_load_lds(AS1(g), AS3(l), 16, 0, 0);
}

#define SB()      __builtin_amdgcn_sched_barrier(0);
#define BARR()    { __builtin_amdgcn_s_barrier(); __builtin_amdgcn_sched_barrier(0); }
#define VMCNT(n)  { asm volatile("s_waitcnt vmcnt(" #n ")" ::: "memory"); __builtin_amdgcn_sched_barrier(0); }
#define LGKM(n)   { asm volatile("s_waitcnt lgkmcnt(" #n ")" ::: "memory"); __builtin_amdgcn_sched_barrier(0); }

// ============== R8 core (proven 1475us): LDS A+B, counted-vmcnt 2-window ==============
// Used by s256, pv256, and qkv vmode. See R8 notes. 128KiB LDS, 0 bank conflicts.
__device__ __forceinline__ void gemm256(const bf16_t* __restrict__ A, int lda,
                                        const bf16_t* __restrict__ B, int ldb,
                                        int nt, f32x4 acc[8][4], bf16_t* lds) {
  const int t = (int)threadIdx.x;
  const int lane = t & 63, wv = t >> 6;
  const int wr = wv >> 2, wc = wv & 3;
  const int fr = lane & 15, fq = lane >> 4;
  char* ldsb = (char*)lds;

  const int s0 = (t * 16) ^ (((t >> 3) & 7) << 4);
  const int r0 = s0 >> 6, q0 = (s0 >> 4) & 3;
  const bf16_t* gA0 = A + (size_t)r0 * lda + q0 * 8;
  const bf16_t* gA1 = gA0 + (size_t)128 * lda;
  const bf16_t* gB0 = B + (size_t)r0 * ldb + q0 * 8;
  const bf16_t* gB1 = gB0 + (size_t)128 * ldb;

  const int swz = (fr * 64 + fq * 16) ^ (((fr >> 1) & 7) << 4);
  const int abase = wr * 8192 + swz;
  const int bbase = 32768 + wc * 4096 + swz;

  bf16x8 bb[4], aa0[4], aa1[4];

#define STAGE_A(cb, kh, kof) { \
    bf16_t* _d = lds + (cb) * 32768 + (kh) * 8192; \
    gload16(gA0 + (kof) + (kh) * 32, _d + t * 8); \
    gload16(gA1 + (kof) + (kh) * 32, _d + 4096 + t * 8); \
  } SB()
#define STAGE_B(cb, kh, kof) { \
    bf16_t* _d = lds + (cb) * 32768 + 16384 + (kh) * 8192; \
    gload16(gB0 + (kof) + (kh) * 32, _d + t * 8); \
    gload16(gB1 + (kof) + (kh) * 32, _d + 4096 + t * 8); \
  } SB()
#define READ_B(cb, kh) { \
    const char* _b = ldsb + (cb) * 65536 + (kh) * 16384 + bbase; \
    _Pragma("unroll") for (int n = 0; n < 4; ++n) bb[n] = *(const bf16x8*)(_b + n * 1024); }
#define READ_A(cb, kh, qm, dst) { \
    const char* _a = ldsb + (cb) * 65536 + (kh) * 16384 + abase + (qm) * 4096; \
    _Pragma("unroll") for (int i = 0; i < 4; ++i) dst[i] = *(const bf16x8*)(_a + i * 1024); }
#define MFMA16(dst, qm) { \
    __builtin_amdgcn_s_setprio(1); \
    _Pragma("unroll") for (int i = 0; i < 4; ++i) \
      _Pragma("unroll") for (int n = 0; n < 4; ++n) \
        acc[(qm) * 4 + i][n] = __builtin_amdgcn_mfma_f32_16x16x32_bf16(dst[i], bb[n], acc[(qm) * 4 + i][n], 0, 0, 0); \
    __builtin_amdgcn_s_setprio(0); }

  STAGE_A(0, 0, 0) STAGE_B(0, 0, 0) STAGE_A(0, 1, 0) STAGE_B(0, 1, 0)

  int kof = 64;
  for (int tt = 0; tt < nt - 1; ++tt, kof += 64) {
    const int cb = tt & 1;
    VMCNT(4) BARR()
    READ_B(cb, 0) READ_A(cb, 0, 0, aa0)
    STAGE_A(cb ^ 1, 0, kof)
    READ_A(cb, 0, 1, aa1)
    STAGE_B(cb ^ 1, 0, kof)
    LGKM(4) MFMA16(aa0, 0)
    LGKM(0) MFMA16(aa1, 1)
    VMCNT(4) BARR()
    READ_B(cb, 1) READ_A(cb, 1, 0, aa0)
    STAGE_A(cb ^ 1, 1, kof)
    READ_A(cb, 1, 1, aa1)
    STAGE_B(cb ^ 1, 1, kof)
    LGKM(4) MFMA16(aa0, 0)
    LGKM(0) MFMA16(aa1, 1)
  }
  {
    const int cb = (nt - 1) & 1;
    VMCNT(4) BARR()
    READ_B(cb, 0) READ_A(cb, 0, 0, aa0) READ_A(cb, 0, 1, aa1)
    LGKM(4) MFMA16(aa0, 0)
    LGKM(0) MFMA16(aa1, 1)
    VMCNT(0) BARR()
    READ_B(cb, 1) READ_A(cb, 1, 0, aa0) READ_A(cb, 1, 1, aa1)
    LGKM(4) MFMA16(aa0, 0)
    LGKM(0) MFMA16(aa1, 1)
  }
#undef STAGE_A
#undef STAGE_B
#undef READ_B
#undef READ_A
#undef MFMA16
}

// ========== NEW core: A via LDS (32KB), B from PACKED weights via registers ==========
// Packed B layout: [panel][kh 0..H-1][cgrp 0..15][lane 0..63][8 bf16]:
//   16B at kh*16KB + cgrp*1KB + lane*16 holds B[col=cgrp*16+(lane&15)][k=kh*32+(lane>>4)*8..+8]
// -> one coalesced global_load_dwordx4 per B-frag, L2-hot, NO barrier dependency.
// LDS traffic per window drops 96KB->64KB per CU (the R8 LDS-BW wall, 256B/clk).
// Sync: vmcnt(0)+barrier per window guards A staging (count-robust: immune to spills);
// lgkm(4)/(0) splits A-frag reads under MFMA; lgkm(0) at window end = WAR guard.
__device__ __forceinline__ void gemm256w(const bf16_t* __restrict__ A, int lda,
                                         const bf16_t* __restrict__ Bp,
                                         int H, f32x4 acc[8][4], bf16_t* lds) {
  const int t = (int)threadIdx.x;
  const int lane = t & 63, wv = t >> 6;
  const int wr = wv >> 2, wc = wv & 3;
  const int fr = lane & 15, fq = lane >> 4;
  char* ldsb = (char*)lds;

  const int s0 = (t * 16) ^ (((t >> 3) & 7) << 4);
  const int r0 = s0 >> 6, q0 = (s0 >> 4) & 3;
  const bf16_t* gA0 = A + (size_t)r0 * lda + q0 * 8;
  const bf16_t* gA1 = gA0 + (size_t)128 * lda;

  const int swz = (fr * 64 + fq * 16) ^ (((fr >> 1) & 7) << 4);
  const int abase = wr * 8192 + swz;            // + buf*16384 + qm*4096 + i*1024 (bytes)
  const bf16_t* gBp = Bp + wc * 2048 + lane * 8;  // + w*8192 + n*512 (elements)

  bf16x8 aa0[4], aa1[4], bbA[4], bbB[4];

#define WSTAGE_A(buf, kof) { \
    bf16_t* _d = lds + (buf) * 8192; \
    gload16(gA0 + (kof), _d + t * 8); \
    gload16(gA1 + (kof), _d + 4096 + t * 8); \
  } SB()
#define WLOADB(set, w) { \
    const bf16_t* _b = gBp + (size_t)(w) * 8192; \
    _Pragma("unroll") for (int n = 0; n < 4; ++n) set[n] = *(const bf16x8*)(_b + n * 512); }
#define WREAD_A(buf, qm, dst) { \
    const char* _a = ldsb + (buf) * 16384 + abase + (qm) * 4096; \
    _Pragma("unroll") for (int i = 0; i < 4; ++i) dst[i] = *(const bf16x8*)(_a + i * 1024); }
#define WMFMA(dst, qm, bset) { \
    _Pragma("unroll") for (int i = 0; i < 4; ++i) \
      _Pragma("unroll") for (int n = 0; n < 4; ++n) \
        acc[(qm) * 4 + i][n] = __builtin_amdgcn_mfma_f32_16x16x32_bf16(dst[i], bset[n], acc[(qm) * 4 + i][n], 0, 0, 0); }

  WSTAGE_A(0, 0) WLOADB(bbA, 0)
  int w = 0;
  for (; w + 2 < H; w += 2) {
    // even window w: buf0, consume bbA; prefetch w+1 -> buf1,bbB
    VMCNT(0) BARR()
    WREAD_A(0, 0, aa0)
    WSTAGE_A(1, (w + 1) * 32) WLOADB(bbB, w + 1)
    WREAD_A(0, 1, aa1)
    LGKM(4)
    __builtin_amdgcn_s_setprio(1); WMFMA(aa0, 0, bbA)
    LGKM(0) WMFMA(aa1, 1, bbA) __builtin_amdgcn_s_setprio(0);
    // odd window w+1: buf1, consume bbB; prefetch w+2 -> buf0,bbA
    VMCNT(0) BARR()
    WREAD_A(1, 0, aa0)
    WSTAGE_A(0, (w + 2) * 32) WLOADB(bbA, w + 2)
    WREAD_A(1, 1, aa1)
    LGKM(4)
    __builtin_amdgcn_s_setprio(1); WMFMA(aa0, 0, bbB)
    LGKM(0) WMFMA(aa1, 1, bbB) __builtin_amdgcn_s_setprio(0);
  }
  // tail: window H-2 (buf0,bbA; stage H-1 -> buf1,bbB), window H-1 (buf1,bbB)
  VMCNT(0) BARR()
  WREAD_A(0, 0, aa0)
  WSTAGE_A(1, (H - 1) * 32) WLOADB(bbB, H - 1)
  WREAD_A(0, 1, aa1)
  LGKM(4)
  __builtin_amdgcn_s_setprio(1); WMFMA(aa0, 0, bbA)
  LGKM(0) WMFMA(aa1, 1, bbA) __builtin_amdgcn_s_setprio(0);
  VMCNT(0) BARR()
  WREAD_A(1, 0, aa0) WREAD_A(1, 1, aa1)
  LGKM(4)
  __builtin_amdgcn_s_setprio(1); WMFMA(aa0, 0, bbB)
  LGKM(0) WMFMA(aa1, 1, bbB) __builtin_amdgcn_s_setprio(0);
#undef WSTAGE_A
#undef WLOADB
#undef WREAD_A
#undef WMFMA
}

#define EPI_VARS \
  const int t = (int)threadIdx.x; \
  const int lane = t & 63, w = t >> 6; \
  const int wr = w >> 2, wc = w & 3; \
  const int fr = lane & 15, fq = lane >> 4;

#define ZERO8x4(acc) \
  _Pragma("unroll") for (int _i = 0; _i < 8; ++_i) \
  _Pragma("unroll") for (int _j = 0; _j < 4; ++_j) { f32x4 _z = {0.f,0.f,0.f,0.f}; acc[_i][_j] = _z; }

// ---------------- conversions ----------------
__global__ void k_cvt(const float* __restrict__ s, bf16_t* __restrict__ d, long n8) {
  long i = (long)blockIdx.x * blockDim.x + threadIdx.x;
  long st = (long)gridDim.x * blockDim.x;
  for (; i < n8; i += st) {
    const float4* sp = (const float4*)(s + i * 8);
    float4 a = sp[0], b = sp[1];
    bf16x8 v;
    v[0] = (__bf16)a.x; v[1] = (__bf16)a.y; v[2] = (__bf16)a.z; v[3] = (__bf16)a.w;
    v[4] = (__bf16)b.x; v[5] = (__bf16)b.y; v[6] = (__bf16)b.z; v[7] = (__bf16)b.w;
    *(bf16x8*)(d + i * 8) = v;
  }
}

// pack fp32 weight (rows=out_features, lda=2048) into MFMA-B-frag order (see gemm256w)
__global__ void k_packw(const float* __restrict__ Wsrc, bf16_t* __restrict__ dst, long nunits) {
  long o = (long)blockIdx.x * blockDim.x + threadIdx.x;
  long st = (long)gridDim.x * blockDim.x;
  for (; o < nunits; o += st) {
    int lane = (int)(o & 63);
    long r = o >> 6;
    int cgrp = (int)(r & 15); r >>= 4;
    int kh = (int)(r & 63);
    long nt = r >> 6;
    int col = (int)nt * 256 + cgrp * 16 + (lane & 15);
    int k = kh * 32 + (lane >> 4) * 8;
    const float* s = Wsrc + (size_t)col * 2048 + k;
    float4 a = ((const float4*)s)[0], b = ((const float4*)s)[1];
    bf16x8 v;
    v[0] = (__bf16)a.x; v[1] = (__bf16)a.y; v[2] = (__bf16)a.z; v[3] = (__bf16)a.w;
    v[4] = (__bf16)b.x; v[5] = (__bf16)b.y; v[6] = (__bf16)b.z; v[7] = (__bf16)b.w;
    *(bf16x8*)(dst + o * 8) = v;
  }
}

__global__ void k_fill(float* o, float v, long n) {
  long i = (long)blockIdx.x * blockDim.x + threadIdx.x;
  long st = (long)gridDim.x * blockDim.x;
  for (; i < n; i += st) o[i] = v;
}

// ---------------- GEMM 1: QKV projection ----------------
// Q/K blocks: new core (packed-W B-regs). V blocks: R8 core (A=Wv linear, B=x).
__global__ __launch_bounds__(512, 2) void k_qkv256(
    const bf16_t* __restrict__ xb, const bf16_t* __restrict__ Wvb,
    const bf16_t* __restrict__ Wpqk,
    const float* __restrict__ bq, const float* __restrict__ bk, const float* __restrict__ bv,
    bf16_t* __restrict__ Q, bf16_t* __restrict__ K, bf16_t* __restrict__ Vt) {
  __shared__ __align__(16) bf16_t lds[65536];
  int bid = (int)blockIdx.x;
  int id = (bid & 7) * 384 + (bid >> 3);  // XCD-bijective swizzle (3072 = 8*384)
  EPI_VARS
  f32x4 acc[8][4];
  ZERO8x4(acc)

  bool vmode = id >= 2048;
  if (!vmode) {
    int mt = id & 127, ntile = id >> 7;  // B-panel-major
    gemm256w(xb + (size_t)mt * 256 * 2048, 2048,
             Wpqk + (size_t)ntile * 524288, 64, acc, lds);
    int sel = ntile >> 3;  // 0 -> Q, 1 -> K
    const float* bias = sel ? bk : bq;
    bf16_t* dst = sel ? K : Q;
    int cbase = (ntile & 7) * 256 + wc * 64;
#pragma unroll
    for (int ni = 0; ni < 4; ++ni) {
      int c2 = cbase + ni * 16 + fr;  // [0,2048)
      int h = c2 >> 10, d = c2 & 1023;
      float bb = bias[c2];
#pragma unroll
      for (int mi = 0; mi < 8; ++mi) {
        f32x4 a = acc[mi][ni];
#pragma unroll
        for (int r = 0; r < 4; ++r) {
          int m = mt * 256 + wr * 128 + mi * 16 + fq * 4 + r;
          int b = m >> 10, tk = m & 1023;
          dst[(((size_t)(b * 2 + h) << 10) + tk) * 1024 + d] = (bf16_t)(a[r] + bb);
        }
      }
    }
  } else {
    int vb = id - 2048;
    int tok = vb & 127, wm = vb >> 7;
    gemm256(Wvb + (size_t)wm * 256 * 2048, 2048,
            xb + (size_t)tok * 256 * 2048, 2048, 32, acc, lds);
#pragma unroll
    for (int mi = 0; mi < 8; ++mi) {
#pragma unroll
      for (int r = 0; r < 4; ++r) {
        int gd = wm * 256 + wr * 128 + mi * 16 + fq * 4 + r;  // [0,2048)
        int h = gd >> 10, dd = gd & 1023;
        float bb = bv[gd];
#pragma unroll
        for (int ni = 0; ni < 4; ++ni) {
          int m = tok * 256 + wc * 64 + ni * 16 + fr;
          int b = m >> 10, tk = m & 1023;
          Vt[(((size_t)(b * 2 + h) << 10) + dd) * 1024 + tk] = (bf16_t)(acc[mi][ni][r] + bb);
        }
      }
    }
  }
}

// ---------------- GEMM 2: S = Q K^T * scale (lower-tri 256-tiles, bf16 out) --------
__global__ __launch_bounds__(512, 2) void k_s256(const bf16_t* __restrict__ Q,
                                                 const bf16_t* __restrict__ K,
                                                 bf16_t* __restrict__ S, int pbase) {
  __shared__ __align__(16) bf16_t lds[65536];
  int id = (int)blockIdx.x;
  int pc = id / 10, rem = id % 10;
  int ti = 0;
  while (rem > ti) { rem -= ti + 1; ++ti; }
  int tj = rem;
  size_t p = (size_t)(pbase + pc);
  EPI_VARS
  f32x4 acc[8][4];
  ZERO8x4(acc)
  gemm256(Q + (p << 20) + (size_t)ti * 256 * 1024, 1024,
          K + (p << 20) + (size_t)tj * 256 * 1024, 1024, 16, acc, lds);
  bf16_t* Sp = S + ((size_t)pc << 20);
  const float scale = 0.022097086912079608f;  // 1/sqrt(2048)
#pragma unroll
  for (int mi = 0; mi < 8; ++mi)
#pragma unroll
    for (int ni = 0; ni < 4; ++ni) {
      int col = tj * 256 + wc * 64 + ni * 16 + fr;
      f32x4 a = acc[mi][ni];
#pragma unroll
      for (int r = 0; r < 4; ++r) {
        int row = ti * 256 + wr * 128 + mi * 16 + fq * 4 + r;
        Sp[((size_t)row << 10) + col] = (bf16_t)(a[r] * scale);
      }
    }
}

// ------- softmax: one ROW per wave (4 rows/block), vectorized bf16x8, causal -------
__global__ __launch_bounds__(256) void k_softmax(const bf16_t* __restrict__ S,
                                                 bf16_t* __restrict__ P) {
  int gw = (int)blockIdx.x * 4 + ((int)threadIdx.x >> 6);
  int pc = gw >> 10, row = gw & 1023;
  int lane = (int)threadIdx.x & 63;
  const bf16_t* s = S + ((size_t)pc << 20) + ((size_t)row << 10);
  bf16_t* p = P + ((size_t)pc << 20) + ((size_t)row << 10);
  int cend = ((row >> 8) + 1) << 8;  // 256-aligned (PV K-tile width)
  bf16x8 v0 = *(const bf16x8*)(s + lane * 8);
  bf16x8 v1 = *(const bf16x8*)(s + 512 + lane * 8);
  float x[16];
  float mx = -1e30f;
#pragma unroll
  for (int j = 0; j < 8; ++j) {
    int c0 = lane * 8 + j, c1 = 512 + lane * 8 + j;
    x[j]     = (c0 <= row) ? (float)v0[j] : -1e30f;
    x[8 + j] = (c1 <= row) ? (float)v1[j] : -1e30f;
    mx = fmaxf(mx, fmaxf(x[j], x[8 + j]));
  }
  for (int o = 32; o > 0; o >>= 1) mx = fmaxf(mx, __shfl_xor(mx, o));
  float sum = 0.f;
#pragma unroll
  for (int j = 0; j < 16; ++j) {
    x[j] = (x[j] > -1e29f) ? __expf(x[j] - mx) : 0.f;
    sum += x[j];
  }
  for (int o = 32; o > 0; o >>= 1) sum += __shfl_xor(sum, o);
  float inv = 1.f / sum;
  bf16x8 o0, o1;
#pragma unroll
  for (int j = 0; j < 8; ++j) {
    o0[j] = (bf16_t)(x[j] * inv);
    o1[j] = (bf16_t)(x[8 + j] * inv);
  }
  if (lane * 8 < cend)       *(bf16x8*)(p + lane * 8) = o0;
  if (512 + lane * 8 < cend) *(bf16x8*)(p + 512 + lane * 8) = o1;
}

// ---------------- GEMM 3: O = P * V (V pre-transposed; causal-shortened K) ---------
__global__ __launch_bounds__(512, 2) void k_pv256(const bf16_t* __restrict__ P,
                                                  const bf16_t* __restrict__ Vt,
                                                  bf16_t* __restrict__ O, int pbase) {
  __shared__ __align__(16) bf16_t lds[65536];
  int id = (int)blockIdx.x;
  int pc = id >> 4, rem = id & 15;
  int ti = rem >> 2, dj = rem & 3;
  size_t p = (size_t)(pbase + pc);
  EPI_VARS
  f32x4 acc[8][4];
  ZERO8x4(acc)
  gemm256(P + ((size_t)pc << 20) + (size_t)ti * 256 * 1024, 1024,
          Vt + (p << 20) + (size_t)dj * 256 * 1024, 1024, (ti + 1) * 4, acc, lds);
  int b = (int)(p >> 1), h = (int)(p & 1);
#pragma unroll
  for (int mi = 0; mi < 8; ++mi)
#pragma unroll
    for (int ni = 0; ni < 4; ++ni) {
      int dcol = dj * 256 + wc * 64 + ni * 16 + fr;
      f32x4 a = acc[mi][ni];
#pragma unroll
      for (int r = 0; r < 4; ++r) {
        int tk = ti * 256 + wr * 128 + mi * 16 + fq * 4 + r;
        O[(((size_t)b << 10) + tk) * 2048 + (h << 10) + dcol] = (bf16_t)a[r];
      }
    }
}

// ---------------- GEMM 4: out = O * Wo^T (fp32 out, packed-W new core) ----------------
__global__ __launch_bounds__(512, 2) void k_out256(const bf16_t* __restrict__ O,
                                                   const bf16_t* __restrict__ Wpo,
                                                   float* __restrict__ out) {
  __shared__ __align__(16) bf16_t lds[16384];  // 32 KiB (A-only staging)
  int bid = (int)blockIdx.x;
  int id = (bid & 7) * 128 + (bid >> 3);  // XCD swizzle (1024 = 8*128)
  int mt = id & 127, ntile = id >> 7;     // B-panel-major
  EPI_VARS
  f32x4 acc[8][4];
  ZERO8x4(acc)
  gemm256w(O + (size_t)mt * 256 * 2048, 2048,
           Wpo + (size_t)ntile * 524288, 64, acc, lds);
#pragma unroll
  for (int mi = 0; mi < 8; ++mi)
#pragma unroll
    for (int ni = 0; ni < 4; ++ni) {
      int col = ntile * 256 + wc * 64 + ni * 16 + fr;
      f32x4 a = acc[mi][ni];
#pragma unroll
      for (int r = 0; r < 4; ++r) {
        int row = mt * 256 + wr * 128 + mi * 16 + fq * 4 + r;
        out[(size_t)row * 2048 + col] = a[r];
      }
    }
}

// ---------------- launch ----------------
extern "C" void kernel_launch(void* const* d_in, const int* in_sizes, int n_in,
                              void* d_out, int out_size, void* d_ws, size_t ws_size,
                              hipStream_t stream) {
  const float* x  = (const float*)d_in[0];
  const float* Wq = (const float*)d_in[1];
  const float* bq = (const float*)d_in[2];
  const float* Wk = (const float*)d_in[3];
  const float* bk = (const float*)d_in[4];
  const float* Wv = (const float*)d_in[5];
  const float* bv = (const float*)d_in[6];
  const float* Wo = (const float*)d_in[7];
  float* out = (float*)d_out;

  const size_t MiB = 1ull << 20;
  char* w = (char*)d_ws;
  bf16_t* xb    = (bf16_t*)w;               // 128 MiB, reused as O after QKV
  bf16_t* Ob    = xb;
  bf16_t* Qb    = (bf16_t*)(w + 128 * MiB); // 128 MiB
  bf16_t* Kb    = (bf16_t*)(w + 256 * MiB); // 128 MiB
  bf16_t* Vt    = (bf16_t*)(w + 384 * MiB); // 128 MiB (transposed V)
  bf16_t* Wvb   = (bf16_t*)(w + 512 * MiB); // 8 MiB  linear Wv (vmode A)
  bf16_t* Wpqk  = (bf16_t*)(w + 520 * MiB); // 16 MiB packed Wq(panels 0-7)+Wk(8-15)
  bf16_t* Wpo   = (bf16_t*)(w + 536 * MiB); // 8 MiB  packed Wo
  bf16_t* Sc    = (bf16_t*)(w + 544 * MiB); // NP * 2 MiB (bf16)

  size_t rem = ws_size > 544 * MiB ? ws_size - 544 * MiB : 0;
  int NP = (int)(rem / (4 * MiB));
  if (NP > 64) NP = 64;
  if (NP < 1) {
    k_fill<<<2048, 256, 0, stream>>>(out, (float)(ws_size >> 20), (long)out_size);
    return;
  }
  bf16_t* Pc = (bf16_t*)(w + 544 * MiB + (size_t)NP * 2 * MiB); // NP * 2 MiB

  // conversions / packing to bf16
  k_cvt<<<2048, 256, 0, stream>>>(x, xb, 8388608L);
  k_cvt<<<1024, 256, 0, stream>>>(Wv, Wvb, 524288L);
  k_packw<<<1024, 256, 0, stream>>>(Wq, Wpqk, 524288L);
  k_packw<<<1024, 256, 0, stream>>>(Wk, Wpqk + 4194304, 524288L);
  k_packw<<<1024, 256, 0, stream>>>(Wo, Wpo, 524288L);

  // QKV projection (Q,K via packed-W core; V via R8 core, stored transposed)
  k_qkv256<<<3072, 512, 0, stream>>>(xb, Wvb, Wpqk, bq, bk, bv, Qb, Kb, Vt);

  // attention, chunked over (b,h) pairs to bound scratch
  for (int base = 0; base < 64; base += NP) {
    int np = (64 - base) < NP ? (64 - base) : NP;
    k_s256<<<np * 10, 512, 0, stream>>>(Qb, Kb, Sc, base);
    k_softmax<<<np * 256, 256, 0, stream>>>(Sc, Pc);
    k_pv256<<<np * 16, 512, 0, stream>>>(Pc, Vt, Ob, base);
  }

  // output projection
  k_out256<<<1024, 512, 0, stream>>>(Ob, Wpo, out);
}

// Round 13
// 1474.742 us; speedup vs baseline: 8.4758x; 1.1680x over previous
//
#include <hip/hip_runtime.h>
#include <hip/hip_bf16.h>
#include <stdint.h>

typedef __bf16 bf16_t;
typedef __bf16 bf16x8 __attribute__((ext_vector_type(8)));
typedef float f32x4 __attribute__((ext_vector_type(4)));

#define AS1(p) ((const __attribute__((address_space(1))) void*)(uintptr_t)(p))
#define AS3(p) ((__attribute__((address_space(3))) void*)(uintptr_t)(p))

__device__ __forceinline__ void gload16(const bf16_t* g, bf16_t* l) {
  __builtin_amdgcn_global_load_lds(AS1(g), AS3(l), 16, 0, 0);
}

#define SB()      __builtin_amdgcn_sched_barrier(0);
#define BARR()    { __builtin_amdgcn_s_barrier(); __builtin_amdgcn_sched_barrier(0); }
#define VMCNT(n)  { asm volatile("s_waitcnt vmcnt(" #n ")" ::: "memory"); __builtin_amdgcn_sched_barrier(0); }
#define LGKM(n)   { asm volatile("s_waitcnt lgkmcnt(" #n ")" ::: "memory"); __builtin_amdgcn_sched_barrier(0); }

// ===== 256x256 GEMM core (B^T form), R8: counted-vmcnt 2-window (proven 1475us) =====
// C[m][n] = sum_k A[m][k]*B[n][k]. 512 threads = 8 waves (2M x 4N), per-wave 128x64.
// BK=64 as 2 k-halves; LDS buf: A kh0|A kh1|B kh0|B kh1 (16KB each); 2 bufs = 128 KiB.
// Half layout [256 rows][32 k] bf16, XOR swizzle byte^=((byte>>7)&7)<<4 (write: linear
// LDS dest + pre-swizzled global source; read: same XOR) -> 0 bank conflicts (proven).
// Two windows per K-tile. Window: vmcnt(4) -> BAR -> reads(B 4 + A-qm0 4) -> stage
// A-half(t+1) -> reads(A-qm1 4) -> stage B-half(t+1) -> lgkm(4) -> 16 MFMA -> lgkm(0)
// -> 16 MFMA. Ledger (in-order vmcnt, only gload_lds in loop): pre-wait outstanding
// = 8; each window's vmcnt(4) retires exactly the 2 units it reads (issued 2 windows
// earlier, ~700cy). WAR: stage follows the barrier postdating prior reads' lgkm0.
__device__ __forceinline__ void gemm256(const bf16_t* __restrict__ A, int lda,
                                        const bf16_t* __restrict__ B, int ldb,
                                        int nt, f32x4 acc[8][4], bf16_t* lds) {
  const int t = (int)threadIdx.x;
  const int lane = t & 63, wv = t >> 6;
  const int wr = wv >> 2, wc = wv & 3;
  const int fr = lane & 15, fq = lane >> 4;
  char* ldsb = (char*)lds;

  const int s0 = (t * 16) ^ (((t >> 3) & 7) << 4);
  const int r0 = s0 >> 6, q0 = (s0 >> 4) & 3;
  const bf16_t* gA0 = A + (size_t)r0 * lda + q0 * 8;
  const bf16_t* gA1 = gA0 + (size_t)128 * lda;
  const bf16_t* gB0 = B + (size_t)r0 * ldb + q0 * 8;
  const bf16_t* gB1 = gB0 + (size_t)128 * ldb;

  const int swz = (fr * 64 + fq * 16) ^ (((fr >> 1) & 7) << 4);
  const int abase = wr * 8192 + swz;          // + cb*65536 + kh*16384 + qm*4096
  const int bbase = 32768 + wc * 4096 + swz;  // + cb*65536 + kh*16384

  bf16x8 bb[4], aa0[4], aa1[4];

#define STAGE_A(cb, kh, kof) { \
    bf16_t* _d = lds + (cb) * 32768 + (kh) * 8192; \
    gload16(gA0 + (kof) + (kh) * 32, _d + t * 8); \
    gload16(gA1 + (kof) + (kh) * 32, _d + 4096 + t * 8); \
  } SB()
#define STAGE_B(cb, kh, kof) { \
    bf16_t* _d = lds + (cb) * 32768 + 16384 + (kh) * 8192; \
    gload16(gB0 + (kof) + (kh) * 32, _d + t * 8); \
    gload16(gB1 + (kof) + (kh) * 32, _d + 4096 + t * 8); \
  } SB()
#define READ_B(cb, kh) { \
    const char* _b = ldsb + (cb) * 65536 + (kh) * 16384 + bbase; \
    _Pragma("unroll") for (int n = 0; n < 4; ++n) bb[n] = *(const bf16x8*)(_b + n * 1024); }
#define READ_A(cb, kh, qm, dst) { \
    const char* _a = ldsb + (cb) * 65536 + (kh) * 16384 + abase + (qm) * 4096; \
    _Pragma("unroll") for (int i = 0; i < 4; ++i) dst[i] = *(const bf16x8*)(_a + i * 1024); }
#define MFMA16(dst, qm) { \
    __builtin_amdgcn_s_setprio(1); \
    _Pragma("unroll") for (int i = 0; i < 4; ++i) \
      _Pragma("unroll") for (int n = 0; n < 4; ++n) \
        acc[(qm) * 4 + i][n] = __builtin_amdgcn_mfma_f32_16x16x32_bf16(dst[i], bb[n], acc[(qm) * 4 + i][n], 0, 0, 0); \
    __builtin_amdgcn_s_setprio(0); }

  // prologue: stage tile 0 fully (8 gloads, ledger order Ak0,Bk0,Ak1,Bk1)
  STAGE_A(0, 0, 0) STAGE_B(0, 0, 0) STAGE_A(0, 1, 0) STAGE_B(0, 1, 0)

  int kof = 64;
  for (int tt = 0; tt < nt - 1; ++tt, kof += 64) {
    const int cb = tt & 1;
    // window A (k-half 0)
    VMCNT(4) BARR()
    READ_B(cb, 0) READ_A(cb, 0, 0, aa0)
    STAGE_A(cb ^ 1, 0, kof)
    READ_A(cb, 0, 1, aa1)
    STAGE_B(cb ^ 1, 0, kof)
    LGKM(4) MFMA16(aa0, 0)
    LGKM(0) MFMA16(aa1, 1)
    // window B (k-half 1)
    VMCNT(4) BARR()
    READ_B(cb, 1) READ_A(cb, 1, 0, aa0)
    STAGE_A(cb ^ 1, 1, kof)
    READ_A(cb, 1, 1, aa1)
    STAGE_B(cb ^ 1, 1, kof)
    LGKM(4) MFMA16(aa0, 0)
    LGKM(0) MFMA16(aa1, 1)
  }
  {  // tail tile: no staging; drain 4 then 0
    const int cb = (nt - 1) & 1;
    VMCNT(4) BARR()
    READ_B(cb, 0) READ_A(cb, 0, 0, aa0) READ_A(cb, 0, 1, aa1)
    LGKM(4) MFMA16(aa0, 0)
    LGKM(0) MFMA16(aa1, 1)
    VMCNT(0) BARR()
    READ_B(cb, 1) READ_A(cb, 1, 0, aa0) READ_A(cb, 1, 1, aa1)
    LGKM(4) MFMA16(aa0, 0)
    LGKM(0) MFMA16(aa1, 1)
  }
#undef STAGE_A
#undef STAGE_B
#undef READ_B
#undef READ_A
#undef MFMA16
}

#define EPI_VARS \
  const int t = (int)threadIdx.x; \
  const int lane = t & 63, w = t >> 6; \
  const int wr = w >> 2, wc = w & 3; \
  const int fr = lane & 15, fq = lane >> 4;

#define ZERO8x4(acc) \
  _Pragma("unroll") for (int _i = 0; _i < 8; ++_i) \
  _Pragma("unroll") for (int _j = 0; _j < 4; ++_j) { f32x4 _z = {0.f,0.f,0.f,0.f}; acc[_i][_j] = _z; }

// ---------------- conversions ----------------
__global__ void k_cvt(const float* __restrict__ s, bf16_t* __restrict__ d, long n8) {
  long i = (long)blockIdx.x * blockDim.x + threadIdx.x;
  long st = (long)gridDim.x * blockDim.x;
  for (; i < n8; i += st) {
    const float4* sp = (const float4*)(s + i * 8);
    float4 a = sp[0], b = sp[1];
    bf16x8 v;
    v[0] = (__bf16)a.x; v[1] = (__bf16)a.y; v[2] = (__bf16)a.z; v[3] = (__bf16)a.w;
    v[4] = (__bf16)b.x; v[5] = (__bf16)b.y; v[6] = (__bf16)b.z; v[7] = (__bf16)b.w;
    *(bf16x8*)(d + i * 8) = v;
  }
}

// merged weight conversion: [Wq|Wk|Wv|Wo] (4 x 4194304 fp32) -> contiguous bf16 dst
__global__ void k_cvtw(const float* __restrict__ Wq, const float* __restrict__ Wk,
                       const float* __restrict__ Wv, const float* __restrict__ Wo,
                       bf16_t* __restrict__ d) {
  long i = (long)blockIdx.x * blockDim.x + threadIdx.x;
  long st = (long)gridDim.x * blockDim.x;
  for (; i < 2097152L; i += st) {
    int r = (int)(i >> 19);
    const float* s = (r == 0 ? Wq : r == 1 ? Wk : r == 2 ? Wv : Wo) + (i & 524287L) * 8;
    float4 a = ((const float4*)s)[0], b = ((const float4*)s)[1];
    bf16x8 v;
    v[0] = (__bf16)a.x; v[1] = (__bf16)a.y; v[2] = (__bf16)a.z; v[3] = (__bf16)a.w;
    v[4] = (__bf16)b.x; v[5] = (__bf16)b.y; v[6] = (__bf16)b.z; v[7] = (__bf16)b.w;
    *(bf16x8*)(d + i * 8) = v;
  }
}

__global__ void k_fill(float* o, float v, long n) {
  long i = (long)blockIdx.x * blockDim.x + threadIdx.x;
  long st = (long)gridDim.x * blockDim.x;
  for (; i < n; i += st) o[i] = v;
}

// ---------------- GEMM 1: QKV projection (256-tile) ----------------
__global__ __launch_bounds__(512, 2) void k_qkv256(
    const bf16_t* __restrict__ xb, const bf16_t* __restrict__ Wb,
    const float* __restrict__ bq, const float* __restrict__ bk, const float* __restrict__ bv,
    bf16_t* __restrict__ Q, bf16_t* __restrict__ K, bf16_t* __restrict__ Vt) {
  __shared__ __align__(16) bf16_t lds[65536];
  int bid = (int)blockIdx.x;
  int id = (bid & 7) * 384 + (bid >> 3);  // XCD-bijective swizzle (3072 = 8*384)
  EPI_VARS
  f32x4 acc[8][4];
  ZERO8x4(acc)

  bool vmode = id >= 2048;
  int mt = 0, ntile = 0, tok = 0, wm = 0;
  const bf16_t *Ap, *Bp;
  if (!vmode) {
    mt = id & 127; ntile = id >> 7;  // B-panel-major: resident blocks share W panel
    Ap = xb + (size_t)mt * 256 * 2048;
    Bp = Wb + (size_t)ntile * 256 * 2048;
  } else {
    int vb = id - 2048;
    tok = vb & 127; wm = vb >> 7;
    Ap = Wb + (size_t)(16 + wm) * 256 * 2048;
    Bp = xb + (size_t)tok * 256 * 2048;
  }
  gemm256(Ap, 2048, Bp, 2048, 32, acc, lds);

  if (!vmode) {
    int sel = ntile >> 3;  // 0 -> Q, 1 -> K
    const float* bias = sel ? bk : bq;
    bf16_t* dst = sel ? K : Q;
    int cbase = (ntile & 7) * 256 + wc * 64;
#pragma unroll
    for (int ni = 0; ni < 4; ++ni) {
      int c2 = cbase + ni * 16 + fr;  // [0,2048)
      int h = c2 >> 10, d = c2 & 1023;
      float bb = bias[c2];
#pragma unroll
      for (int mi = 0; mi < 8; ++mi) {
        f32x4 a = acc[mi][ni];
#pragma unroll
        for (int r = 0; r < 4; ++r) {
          int m = mt * 256 + wr * 128 + mi * 16 + fq * 4 + r;
          int b = m >> 10, tk = m & 1023;
          dst[(((size_t)(b * 2 + h) << 10) + tk) * 1024 + d] = (bf16_t)(a[r] + bb);
        }
      }
    }
  } else {
#pragma unroll
    for (int mi = 0; mi < 8; ++mi) {
#pragma unroll
      for (int r = 0; r < 4; ++r) {
        int gd = wm * 256 + wr * 128 + mi * 16 + fq * 4 + r;  // [0,2048)
        int h = gd >> 10, dd = gd & 1023;
        float bb = bv[gd];
#pragma unroll
        for (int ni = 0; ni < 4; ++ni) {
          int m = tok * 256 + wc * 64 + ni * 16 + fr;
          int b = m >> 10, tk = m & 1023;
          Vt[(((size_t)(b * 2 + h) << 10) + dd) * 1024 + tk] = (bf16_t)(acc[mi][ni][r] + bb);
        }
      }
    }
  }
}

// ---------------- GEMM 2: S = Q K^T * scale (lower-tri 256-tiles, bf16 out) --------
__global__ __launch_bounds__(512, 2) void k_s256(const bf16_t* __restrict__ Q,
                                                 const bf16_t* __restrict__ K,
                                                 bf16_t* __restrict__ S, int pbase) {
  __shared__ __align__(16) bf16_t lds[65536];
  int id = (int)blockIdx.x;
  int pc = id / 10, rem = id % 10;
  int ti = 0;
  while (rem > ti) { rem -= ti + 1; ++ti; }
  int tj = rem;
  size_t p = (size_t)(pbase + pc);
  EPI_VARS
  f32x4 acc[8][4];
  ZERO8x4(acc)
  gemm256(Q + (p << 20) + (size_t)ti * 256 * 1024, 1024,
          K + (p << 20) + (size_t)tj * 256 * 1024, 1024, 16, acc, lds);
  bf16_t* Sp = S + ((size_t)pc << 20);
  const float scale = 0.022097086912079608f;  // 1/sqrt(2048)
#pragma unroll
  for (int mi = 0; mi < 8; ++mi)
#pragma unroll
    for (int ni = 0; ni < 4; ++ni) {
      int col = tj * 256 + wc * 64 + ni * 16 + fr;
      f32x4 a = acc[mi][ni];
#pragma unroll
      for (int r = 0; r < 4; ++r) {
        int row = ti * 256 + wr * 128 + mi * 16 + fq * 4 + r;
        Sp[((size_t)row << 10) + col] = (bf16_t)(a[r] * scale);
      }
    }
}

// --- softmax: one ROW per wave, vectorized bf16x8, causal, IN-PLACE (P == S) ---
// Safe in-place: each lane loads its row segments to registers before any store;
// rows are disjoint across waves; cend == (ti+1)*256 == pv's kdim for every row.
__global__ __launch_bounds__(256) void k_softmax(const bf16_t* __restrict__ S,
                                                 bf16_t* __restrict__ P) {
  int gw = (int)blockIdx.x * 4 + ((int)threadIdx.x >> 6);
  int pc = gw >> 10, row = gw & 1023;
  int lane = (int)threadIdx.x & 63;
  const bf16_t* s = S + ((size_t)pc << 20) + ((size_t)row << 10);
  bf16_t* p = P + ((size_t)pc << 20) + ((size_t)row << 10);
  int cend = ((row >> 8) + 1) << 8;  // 256-aligned (PV K-tile width)
  bf16x8 v0 = *(const bf16x8*)(s + lane * 8);
  bf16x8 v1 = *(const bf16x8*)(s + 512 + lane * 8);
  float x[16];
  float mx = -1e30f;
#pragma unroll
  for (int j = 0; j < 8; ++j) {
    int c0 = lane * 8 + j, c1 = 512 + lane * 8 + j;
    x[j]     = (c0 <= row) ? (float)v0[j] : -1e30f;
    x[8 + j] = (c1 <= row) ? (float)v1[j] : -1e30f;
    mx = fmaxf(mx, fmaxf(x[j], x[8 + j]));
  }
  for (int o = 32; o > 0; o >>= 1) mx = fmaxf(mx, __shfl_xor(mx, o));
  float sum = 0.f;
#pragma unroll
  for (int j = 0; j < 16; ++j) {
    x[j] = (x[j] > -1e29f) ? __expf(x[j] - mx) : 0.f;
    sum += x[j];
  }
  for (int o = 32; o > 0; o >>= 1) sum += __shfl_xor(sum, o);
  float inv = 1.f / sum;
  bf16x8 o0, o1;
#pragma unroll
  for (int j = 0; j < 8; ++j) {
    o0[j] = (bf16_t)(x[j] * inv);
    o1[j] = (bf16_t)(x[8 + j] * inv);
  }
  if (lane * 8 < cend)       *(bf16x8*)(p + lane * 8) = o0;
  if (512 + lane * 8 < cend) *(bf16x8*)(p + 512 + lane * 8) = o1;
}

// ---------------- GEMM 3: O = P * V (V pre-transposed; causal-shortened K) ---------
__global__ __launch_bounds__(512, 2) void k_pv256(const bf16_t* __restrict__ P,
                                                  const bf16_t* __restrict__ Vt,
                                                  bf16_t* __restrict__ O, int pbase) {
  __shared__ __align__(16) bf16_t lds[65536];
  int id = (int)blockIdx.x;
  int pc = id >> 4, rem = id & 15;
  int ti = rem >> 2, dj = rem & 3;
  size_t p = (size_t)(pbase + pc);
  EPI_VARS
  f32x4 acc[8][4];
  ZERO8x4(acc)
  gemm256(P + ((size_t)pc << 20) + (size_t)ti * 256 * 1024, 1024,
          Vt + (p << 20) + (size_t)dj * 256 * 1024, 1024, (ti + 1) * 4, acc, lds);
  int b = (int)(p >> 1), h = (int)(p & 1);
#pragma unroll
  for (int mi = 0; mi < 8; ++mi)
#pragma unroll
    for (int ni = 0; ni < 4; ++ni) {
      int dcol = dj * 256 + wc * 64 + ni * 16 + fr;
      f32x4 a = acc[mi][ni];
#pragma unroll
      for (int r = 0; r < 4; ++r) {
        int tk = ti * 256 + wr * 128 + mi * 16 + fq * 4 + r;
        O[(((size_t)b << 10) + tk) * 2048 + (h << 10) + dcol] = (bf16_t)a[r];
      }
    }
}

// ---------------- GEMM 4: out = O * Wo^T (fp32 out) ----------------
__global__ __launch_bounds__(512, 2) void k_out256(const bf16_t* __restrict__ O,
                                                   const bf16_t* __restrict__ W,
                                                   float* __restrict__ out) {
  __shared__ __align__(16) bf16_t lds[65536];
  int bid = (int)blockIdx.x;
  int id = (bid & 7) * 128 + (bid >> 3);  // XCD swizzle (1024 = 8*128)
  int mt = id & 127, ntile = id >> 7;     // B-panel-major
  EPI_VARS
  f32x4 acc[8][4];
  ZERO8x4(acc)
  gemm256(O + (size_t)mt * 256 * 2048, 2048, W + (size_t)ntile * 256 * 2048, 2048, 32, acc, lds);
#pragma unroll
  for (int mi = 0; mi < 8; ++mi)
#pragma unroll
    for (int ni = 0; ni < 4; ++ni) {
      int col = ntile * 256 + wc * 64 + ni * 16 + fr;
      f32x4 a = acc[mi][ni];
#pragma unroll
      for (int r = 0; r < 4; ++r) {
        int row = mt * 256 + wr * 128 + mi * 16 + fq * 4 + r;
        out[(size_t)row * 2048 + col] = a[r];
      }
    }
}

// ---------------- launch ----------------
extern "C" void kernel_launch(void* const* d_in, const int* in_sizes, int n_in,
                              void* d_out, int out_size, void* d_ws, size_t ws_size,
                              hipStream_t stream) {
  const float* x  = (const float*)d_in[0];
  const float* Wq = (const float*)d_in[1];
  const float* bq = (const float*)d_in[2];
  const float* Wk = (const float*)d_in[3];
  const float* bk = (const float*)d_in[4];
  const float* Wv = (const float*)d_in[5];
  const float* bv = (const float*)d_in[6];
  const float* Wo = (const float*)d_in[7];
  float* out = (float*)d_out;

  const size_t MiB = 1ull << 20;
  char* w = (char*)d_ws;
  bf16_t* xb    = (bf16_t*)w;               // 128 MiB, reused as O after QKV
  bf16_t* Ob    = xb;
  bf16_t* Qb    = (bf16_t*)(w + 128 * MiB); // 128 MiB
  bf16_t* Kb    = (bf16_t*)(w + 256 * MiB); // 128 MiB
  bf16_t* Vt    = (bf16_t*)(w + 384 * MiB); // 128 MiB (transposed V)
  bf16_t* Wqkvb = (bf16_t*)(w + 512 * MiB); // 24 MiB  [Wq;Wk;Wv] (+ Wo after -> 32 MiB)
  bf16_t* Wob   = (bf16_t*)(w + 536 * MiB); // 8 MiB (contiguous after Wqkvb)
  bf16_t* Sc    = (bf16_t*)(w + 544 * MiB); // NP * 2 MiB (bf16; softmax in-place)

  size_t rem = ws_size > 544 * MiB ? ws_size - 544 * MiB : 0;
  int NP = (int)(rem / (2 * MiB));
  if (NP > 64) NP = 64;
  if (NP < 1) {
    k_fill<<<2048, 256, 0, stream>>>(out, (float)(ws_size >> 20), (long)out_size);
    return;
  }

  // conversions to bf16 (x; then all four weights in one launch - dst contiguous)
  k_cvt<<<2048, 256, 0, stream>>>(x, xb, 8388608L);
  k_cvtw<<<2048, 256, 0, stream>>>(Wq, Wk, Wv, Wo, Wqkvb);

  // QKV projection (Q,K normal layout; V transposed)
  k_qkv256<<<3072, 512, 0, stream>>>(xb, Wqkvb, bq, bk, bv, Qb, Kb, Vt);

  // attention, chunked over (b,h) pairs to bound scratch (softmax in-place: P == S)
  for (int base = 0; base < 64; base += NP) {
    int np = (64 - base) < NP ? (64 - base) : NP;
    k_s256<<<np * 10, 512, 0, stream>>>(Qb, Kb, Sc, base);
    k_softmax<<<np * 256, 256, 0, stream>>>(Sc, Sc);
    k_pv256<<<np * 16, 512, 0, stream>>>(Sc, Vt, Ob, base);
  }

  // output projection
  k_out256<<<1024, 512, 0, stream>>>(Ob, Wob, out);
}